// Round 10
// baseline (73.508 us; speedup 1.0000x reference)
//
#include <hip/hip_runtime.h>
#include <hip/hip_bf16.h>

#define B_ 8
#define C_ 512
#define N_ 4096
#define D_ 64
#define HID_ 100

typedef short bf16x8 __attribute__((ext_vector_type(8)));
typedef short bf16x4 __attribute__((ext_vector_type(4)));
typedef float f32x4 __attribute__((ext_vector_type(4)));

__device__ __forceinline__ short f2bf(float f) {
  unsigned u = __builtin_bit_cast(unsigned, f);
  u += 0x7fff + ((u >> 16) & 1);   // round-to-nearest-even
  return (short)(u >> 16);
}

__device__ __forceinline__ float fast_tanh(float x) {
  float cx = fminf(fmaxf(x, -15.f), 15.f);
  float a = exp2f(cx * 2.885390082f);           // e^{2x}
  return (a - 1.f) * __builtin_amdgcn_rcpf(a + 1.f);
}

// ---------------------------------------------------------------------------
// General path (gamma != 0): q/k/v projections + full attention.
// Early-exit when gamma == 0 (the benched inputs) -> small grids.
// ---------------------------------------------------------------------------

__global__ __launch_bounds__(256) void qkv_proj(
    const float* __restrict__ x,
    const float* __restrict__ Wq, const float* __restrict__ bq,
    const float* __restrict__ Wk, const float* __restrict__ bk,
    const float* __restrict__ Wv, const float* __restrict__ bv,
    const float* __restrict__ gamma,
    float* __restrict__ q, float* __restrict__ k, float* __restrict__ v) {
  if (gamma[0] == 0.0f) return;
  const int ROWS = D_ + D_ + C_;
  const int TILES = N_ / 256;
  const int NJOBS = B_ * ROWS * TILES;
  for (int job = blockIdx.x; job < NJOBS; job += gridDim.x) {
    int tile = job % TILES;
    int row  = (job / TILES) % ROWS;
    int b    = job / (TILES * ROWS);
    int n = tile * 256 + threadIdx.x;
    const float* W;
    float bias;
    float* dst;
    if (row < D_) {
      W = Wq + (size_t)row * C_; bias = bq[row];
      dst = q + ((size_t)b * D_ + row) * N_;
    } else if (row < 2 * D_) {
      int r = row - D_;
      W = Wk + (size_t)r * C_; bias = bk[r];
      dst = k + ((size_t)b * D_ + r) * N_;
    } else {
      int r = row - 2 * D_;
      W = Wv + (size_t)r * C_; bias = bv[r];
      dst = v + ((size_t)b * C_ + r) * N_;
    }
    const float* xb = x + (size_t)b * C_ * N_ + n;
    float s = 0.f;
    for (int c = 0; c < C_; ++c) s += W[c] * xb[(size_t)c * N_];
    dst[n] = s + bias;
  }
}

__global__ __launch_bounds__(256) void attn_sa(
    const float* __restrict__ q, const float* __restrict__ k,
    const float* __restrict__ v, const float* __restrict__ gamma,
    float* __restrict__ sa) {
  if (gamma[0] == 0.0f) return;
  __shared__ float e[N_];
  __shared__ float qi[D_];
  __shared__ float red4[4];
  const int tid = threadIdx.x;
  for (int job = blockIdx.x; job < B_ * N_; job += gridDim.x) {
    int b = job >> 12;
    int i = job & (N_ - 1);
    if (tid < D_) qi[tid] = q[((size_t)b * D_ + tid) * N_ + i];
    __syncthreads();
    for (int j = tid; j < N_; j += 256) {
      float s = 0.f;
      for (int d = 0; d < D_; ++d) s += qi[d] * k[((size_t)b * D_ + d) * N_ + j];
      e[j] = s;
    }
    __syncthreads();
    float m = -1e30f;
    for (int j = tid; j < N_; j += 256) m = fmaxf(m, e[j]);
#pragma unroll
    for (int off = 32; off; off >>= 1) m = fmaxf(m, __shfl_xor(m, off));
    if ((tid & 63) == 0) red4[tid >> 6] = m;
    __syncthreads();
    float M = fmaxf(fmaxf(red4[0], red4[1]), fmaxf(red4[2], red4[3]));
    __syncthreads();
    float ssum = 0.f;
    for (int j = tid; j < N_; j += 256) {
      float p = expf(e[j] - M);
      e[j] = p;
      ssum += p;
    }
#pragma unroll
    for (int off = 32; off; off >>= 1) ssum += __shfl_xor(ssum, off);
    if ((tid & 63) == 0) red4[tid >> 6] = ssum;
    __syncthreads();
    float inv = 1.0f / (red4[0] + red4[1] + red4[2] + red4[3]);
    __syncthreads();
    for (int c = tid; c < C_; c += 256) {
      const float* vr = v + ((size_t)b * C_ + c) * N_;
      float s = 0.f;
      for (int j = 0; j < N_; ++j) s += vr[j] * e[j];
      sa[((size_t)b * C_ + c) * N_ + i] = s * inv;
    }
    __syncthreads();
  }
}

// ---------------------------------------------------------------------------
// Wa f32 -> bf16 pre-convert, padded to 128 h-rows (rows 100..127 zero).
// ---------------------------------------------------------------------------
__global__ __launch_bounds__(256) void wa_to_bf16(
    const float* __restrict__ Wa, short* __restrict__ wab) {
  int flat = (blockIdx.x * 256 + threadIdx.x) * 4;   // over 128*512
  int h = flat >> 9, c = flat & 511;
  bf16x4 p = {0, 0, 0, 0};
  if (h < HID_) {
    float4 w4 = *(const float4*)&Wa[(size_t)h * C_ + c];
    p = (bf16x4){f2bf(w4.x), f2bf(w4.y), f2bf(w4.z), f2bf(w4.w)};
  }
  *(bf16x4*)&wab[flat] = p;
}

// ---------------------------------------------------------------------------
// score[b,n] = Wc . tanh(Wa @ hfeat[b,:,n] + ba)
// ONE barrier. Whole 128n x 512c x-tile staged once as bf16 [n][k] in LDS
// with XOR swizzle byte ^= ((n&7)<<4):
//   - staging: thread owns n = tid&127 (256B-coalesced global reads), 4
//     k-octets per pass -> b128 LDS writes, n&7 full diversity (2-way, free)
//   - A-frag: one ds_read_b128 per (nfrag,kstep), reused for 4 hfrags
// B (wab) read EXACTLY ONCE per block from L2 (was the hidden 256MB tax).
// Grid: 8 b x 32 n-tiles of 128 = 256 blocks. Block: 1024 thr = 16 waves
//   = 8 nfrags(16n) x 2 h-halves(4 hfrags). Barrier-free compute loop.
// ---------------------------------------------------------------------------

__global__ __launch_bounds__(1024, 4) void pool_gemm(
    const float* __restrict__ x, const float* __restrict__ sa,
    const float* __restrict__ gamma,
    const short* __restrict__ wab, const float* __restrict__ ba,
    const float* __restrict__ Wc, float* __restrict__ score) {
  __shared__ short xls[128 * 512];     // 128 KB, [n][k] bf16, XOR-swizzled
  __shared__ float red[2][128];

  const int tid  = threadIdx.x;
  const int lane = tid & 63;
  const int w    = tid >> 6;       // 0..15
  const int nf   = w & 7;          // nfrag (16 n)
  const int hh   = w >> 3;         // h-half: hfrags 4hh..4hh+3
  const int r16  = lane & 15;
  const int gq   = lane >> 4;      // 0..3
  const int b    = blockIdx.x >> 5;
  const int n0   = (blockIdx.x & 31) * 128;
  const float g  = gamma[0];

  // ---- staging: thread owns n = tid&127; passes over k-octets ----
  const int sn = tid & 127;
  const int g4 = tid >> 7;         // 0..7
  const int swz = (sn & 7) << 4;
  const float* xb  = x  + (size_t)b * C_ * N_ + n0 + sn;
  const float* sab = sa + (size_t)b * C_ * N_ + n0 + sn;

#pragma unroll
  for (int pass = 0; pass < 2; ++pass) {
    float v[4][8];
#pragma unroll
    for (int i = 0; i < 4; ++i) {
      const int cbase = 256 * pass + 8 * g4 + 64 * i;
#pragma unroll
      for (int e = 0; e < 8; ++e)
        v[i][e] = xb[(size_t)(cbase + e) * N_];
    }
    if (g != 0.0f) {
#pragma unroll
      for (int i = 0; i < 4; ++i) {
        const int cbase = 256 * pass + 8 * g4 + 64 * i;
#pragma unroll
        for (int e = 0; e < 8; ++e)
          v[i][e] += g * sab[(size_t)(cbase + e) * N_];
      }
    }
#pragma unroll
    for (int i = 0; i < 4; ++i) {
      const int oct = 32 * pass + g4 + 8 * i;
      bf16x8 pk;
#pragma unroll
      for (int e = 0; e < 8; ++e) pk[e] = f2bf(v[i][e]);
      *(bf16x8*)&xls[sn * 512 + (((oct * 16) ^ swz) >> 1)] = pk;
    }
  }
  __syncthreads();   // the ONLY barrier

  // ---- compute: 16 ksteps, no barriers ----
  const int arow = nf * 16 + r16;
  const short* abase = &xls[arow * 512];
  const int aswz = (arow & 7) << 4;
  const short* wpr = wab + (size_t)(hh * 64 + r16) * C_ + 8 * gq;

  f32x4 acc[4];
#pragma unroll
  for (int f = 0; f < 4; ++f) acc[f] = (f32x4){0.f, 0.f, 0.f, 0.f};

#pragma unroll
  for (int ks = 0; ks < 16; ++ks) {
    bf16x8 af = *(const bf16x8*)&abase[((((4 * ks + gq) * 16) ^ aswz) >> 1)];
#pragma unroll
    for (int f = 0; f < 4; ++f) {
      bf16x8 bfr = *(const bf16x8*)&wpr[(size_t)(f * 16) * C_ + ks * 32];
      acc[f] =
          __builtin_amdgcn_mfma_f32_16x16x32_bf16(af, bfr, acc[f], 0, 0, 0);
    }
  }

  // epilogue: lane holds D[n = n0 + nf*16 + gq*4 + j][h = hh*64 + f*16 + r16]
  float wcv[4], bav[4];
#pragma unroll
  for (int f = 0; f < 4; ++f) {
    int h = hh * 64 + f * 16 + r16;
    wcv[f] = (h < HID_) ? Wc[h] : 0.f;
    bav[f] = (h < HID_) ? ba[h] : 0.f;
  }
  f32x4 part = {0.f, 0.f, 0.f, 0.f};
#pragma unroll
  for (int f = 0; f < 4; ++f) {
#pragma unroll
    for (int j = 0; j < 4; ++j)
      part[j] += wcv[f] * fast_tanh(acc[f][j] + bav[f]);
  }
#pragma unroll
  for (int off = 1; off < 16; off <<= 1) {
#pragma unroll
    for (int j = 0; j < 4; ++j) part[j] += __shfl_xor(part[j], off);
  }
  if (r16 == 0)
    *(f32x4*)&red[hh][nf * 16 + gq * 4] = part;
  __syncthreads();
  if (tid < 128)
    score[(size_t)b * N_ + n0 + tid] = red[0][tid] + red[1][tid];
}

// softmax over n per batch
__global__ __launch_bounds__(256) void softmax_n(
    const float* __restrict__ score, float* __restrict__ amap) {
  const int b = blockIdx.x;
  const int tid = threadIdx.x;
  __shared__ float red4[4];
  float m = -1e30f;
  for (int i = tid; i < N_; i += 256) m = fmaxf(m, score[(size_t)b * N_ + i]);
#pragma unroll
  for (int off = 32; off; off >>= 1) m = fmaxf(m, __shfl_xor(m, off));
  if ((tid & 63) == 0) red4[tid >> 6] = m;
  __syncthreads();
  float M = fmaxf(fmaxf(red4[0], red4[1]), fmaxf(red4[2], red4[3]));
  __syncthreads();
  float s = 0.f;
  for (int i = tid; i < N_; i += 256) s += expf(score[(size_t)b * N_ + i] - M);
#pragma unroll
  for (int off = 32; off; off >>= 1) s += __shfl_xor(s, off);
  if ((tid & 63) == 0) red4[tid >> 6] = s;
  __syncthreads();
  float inv = 1.0f / (red4[0] + red4[1] + red4[2] + red4[3]);
  for (int i = tid; i < N_; i += 256)
    amap[(size_t)b * N_ + i] = expf(score[(size_t)b * N_ + i] - M) * inv;
}

// out[b,c] = sum_n x[b,c,n] * amap[b,n]
__global__ __launch_bounds__(256) void wsum_kernel(
    const float* __restrict__ x, const float* __restrict__ amap,
    float* __restrict__ out) {
  const int b = blockIdx.x >> 9;
  const int c = blockIdx.x & 511;
  const float4* xr = (const float4*)(x + ((size_t)b * C_ + c) * N_);
  const float4* am = (const float4*)(amap + (size_t)b * N_);
  float s = 0.f;
  for (int i = threadIdx.x; i < N_ / 4; i += 256) {
    float4 xv = xr[i];
    float4 av = am[i];
    s += xv.x * av.x + xv.y * av.y + xv.z * av.z + xv.w * av.w;
  }
#pragma unroll
  for (int off = 32; off; off >>= 1) s += __shfl_xor(s, off);
  __shared__ float red4[4];
  if ((threadIdx.x & 63) == 0) red4[threadIdx.x >> 6] = s;
  __syncthreads();
  if (threadIdx.x == 0)
    out[blockIdx.x] = red4[0] + red4[1] + red4[2] + red4[3];
}

extern "C" void kernel_launch(void* const* d_in, const int* in_sizes, int n_in,
                              void* d_out, int out_size, void* d_ws, size_t ws_size,
                              hipStream_t stream) {
  const float* x     = (const float*)d_in[0];
  const float* Wq    = (const float*)d_in[1];
  const float* bq    = (const float*)d_in[2];
  const float* Wk    = (const float*)d_in[3];
  const float* bk    = (const float*)d_in[4];
  const float* Wv    = (const float*)d_in[5];
  const float* bv    = (const float*)d_in[6];
  const float* gamma = (const float*)d_in[7];
  const float* Wa    = (const float*)d_in[8];
  const float* ba    = (const float*)d_in[9];
  const float* Wc    = (const float*)d_in[10];
  float* out = (float*)d_out;

  float* ws    = (float*)d_ws;
  float* score = ws;                          // B*N floats
  float* amap  = ws + 32768;                  // B*N floats
  short* wab   = (short*)(ws + 65536);        // 128*512 shorts (+slack)
  float* q  = ws + 65536 + 40960;
  float* k  = q + (size_t)B_ * D_ * N_;
  float* v  = k + (size_t)B_ * D_ * N_;
  float* sa = v + (size_t)B_ * C_ * N_;

  wa_to_bf16<<<64, 256, 0, stream>>>(Wa, wab);
  qkv_proj<<<256, 256, 0, stream>>>(x, Wq, bq, Wk, bk, Wv, bv, gamma, q, k, v);
  attn_sa<<<256, 256, 0, stream>>>(q, k, v, gamma, sa);
  pool_gemm<<<B_ * (N_ / 128), 1024, 0, stream>>>(x, sa, gamma, wab, ba, Wc, score);
  softmax_n<<<B_, 256, 0, stream>>>(score, amap);
  wsum_kernel<<<B_ * C_, 256, 0, stream>>>(x, amap, out);
}

// Round 11
// 68.649 us; speedup vs baseline: 1.0708x; 1.0708x over previous
//
#include <hip/hip_runtime.h>
#include <hip/hip_bf16.h>

#define B_ 8
#define C_ 512
#define N_ 4096
#define D_ 64
#define HID_ 100

typedef short bf16x8 __attribute__((ext_vector_type(8)));
typedef short bf16x4 __attribute__((ext_vector_type(4)));
typedef float f32x4 __attribute__((ext_vector_type(4)));

__device__ __forceinline__ short f2bf(float f) {
  unsigned u = __builtin_bit_cast(unsigned, f);
  u += 0x7fff + ((u >> 16) & 1);   // round-to-nearest-even
  return (short)(u >> 16);
}

__device__ __forceinline__ float fast_tanh(float x) {
  float cx = fminf(fmaxf(x, -15.f), 15.f);
  float a = exp2f(cx * 2.885390082f);           // e^{2x}
  return (a - 1.f) * __builtin_amdgcn_rcpf(a + 1.f);
}

// ---------------------------------------------------------------------------
// General path (gamma != 0): q/k/v projections + full attention.
// Early-exit when gamma == 0 (the benched inputs) -> small grids.
// ---------------------------------------------------------------------------

__global__ __launch_bounds__(256) void qkv_proj(
    const float* __restrict__ x,
    const float* __restrict__ Wq, const float* __restrict__ bq,
    const float* __restrict__ Wk, const float* __restrict__ bk,
    const float* __restrict__ Wv, const float* __restrict__ bv,
    const float* __restrict__ gamma,
    float* __restrict__ q, float* __restrict__ k, float* __restrict__ v) {
  if (gamma[0] == 0.0f) return;
  const int ROWS = D_ + D_ + C_;
  const int TILES = N_ / 256;
  const int NJOBS = B_ * ROWS * TILES;
  for (int job = blockIdx.x; job < NJOBS; job += gridDim.x) {
    int tile = job % TILES;
    int row  = (job / TILES) % ROWS;
    int b    = job / (TILES * ROWS);
    int n = tile * 256 + threadIdx.x;
    const float* W;
    float bias;
    float* dst;
    if (row < D_) {
      W = Wq + (size_t)row * C_; bias = bq[row];
      dst = q + ((size_t)b * D_ + row) * N_;
    } else if (row < 2 * D_) {
      int r = row - D_;
      W = Wk + (size_t)r * C_; bias = bk[r];
      dst = k + ((size_t)b * D_ + r) * N_;
    } else {
      int r = row - 2 * D_;
      W = Wv + (size_t)r * C_; bias = bv[r];
      dst = v + ((size_t)b * C_ + r) * N_;
    }
    const float* xb = x + (size_t)b * C_ * N_ + n;
    float s = 0.f;
    for (int c = 0; c < C_; ++c) s += W[c] * xb[(size_t)c * N_];
    dst[n] = s + bias;
  }
}

__global__ __launch_bounds__(256) void attn_sa(
    const float* __restrict__ q, const float* __restrict__ k,
    const float* __restrict__ v, const float* __restrict__ gamma,
    float* __restrict__ sa) {
  if (gamma[0] == 0.0f) return;
  __shared__ float e[N_];
  __shared__ float qi[D_];
  __shared__ float red4[4];
  const int tid = threadIdx.x;
  for (int job = blockIdx.x; job < B_ * N_; job += gridDim.x) {
    int b = job >> 12;
    int i = job & (N_ - 1);
    if (tid < D_) qi[tid] = q[((size_t)b * D_ + tid) * N_ + i];
    __syncthreads();
    for (int j = tid; j < N_; j += 256) {
      float s = 0.f;
      for (int d = 0; d < D_; ++d) s += qi[d] * k[((size_t)b * D_ + d) * N_ + j];
      e[j] = s;
    }
    __syncthreads();
    float m = -1e30f;
    for (int j = tid; j < N_; j += 256) m = fmaxf(m, e[j]);
#pragma unroll
    for (int off = 32; off; off >>= 1) m = fmaxf(m, __shfl_xor(m, off));
    if ((tid & 63) == 0) red4[tid >> 6] = m;
    __syncthreads();
    float M = fmaxf(fmaxf(red4[0], red4[1]), fmaxf(red4[2], red4[3]));
    __syncthreads();
    float ssum = 0.f;
    for (int j = tid; j < N_; j += 256) {
      float p = expf(e[j] - M);
      e[j] = p;
      ssum += p;
    }
#pragma unroll
    for (int off = 32; off; off >>= 1) ssum += __shfl_xor(ssum, off);
    if ((tid & 63) == 0) red4[tid >> 6] = ssum;
    __syncthreads();
    float inv = 1.0f / (red4[0] + red4[1] + red4[2] + red4[3]);
    __syncthreads();
    for (int c = tid; c < C_; c += 256) {
      const float* vr = v + ((size_t)b * C_ + c) * N_;
      float s = 0.f;
      for (int j = 0; j < N_; ++j) s += vr[j] * e[j];
      sa[((size_t)b * C_ + c) * N_ + i] = s * inv;
    }
    __syncthreads();
  }
}

// ---------------------------------------------------------------------------
// Wa f32 -> bf16 pre-convert, padded to 128 h-rows (rows 100..127 zero).
// ---------------------------------------------------------------------------
__global__ __launch_bounds__(256) void wa_to_bf16(
    const float* __restrict__ Wa, short* __restrict__ wab) {
  int flat = (blockIdx.x * 256 + threadIdx.x) * 4;   // over 128*512
  int h = flat >> 9, c = flat & 511;
  bf16x4 p = {0, 0, 0, 0};
  if (h < HID_) {
    float4 w4 = *(const float4*)&Wa[(size_t)h * C_ + c];
    p = (bf16x4){f2bf(w4.x), f2bf(w4.y), f2bf(w4.z), f2bf(w4.w)};
  }
  *(bf16x4*)&wab[flat] = p;
}

// ---------------------------------------------------------------------------
// score[b,n] = Wc . tanh(Wa @ hfeat[b,:,n] + ba)  -- MFMA bf16.
// Structure = the measured-best Round-3 kernel (64n x 64c dbuf tiles,
// 512 blocks x 512 thr, float4-n-contiguous staging), with ONE change:
// A (Wa) fragments are read directly from L2-resident wab (b128) instead of
// being staged through LDS -> LDS 62.5->18 KB, 4 blk/CU, half the LDS ops.
// Block: 8 waves = 2 h-halves (4 hfrags) x 4 n-quarters (16 n).
// ---------------------------------------------------------------------------

#define X_LDH 68

__global__ __launch_bounds__(512, 4) void pool_gemm(
    const float* __restrict__ x, const float* __restrict__ sa,
    const float* __restrict__ gamma,
    const short* __restrict__ wab, const float* __restrict__ ba,
    const float* __restrict__ Wc, float* __restrict__ score) {
  __shared__ short xls[2][64 * X_LDH];
  __shared__ float red[8][16];

  const int tid  = threadIdx.x;
  const int lane = tid & 63;
  const int w    = tid >> 6;       // 0..7
  const int whf  = w >> 2;         // h half: hfrags whf*4 .. +3
  const int wn   = w & 3;          // n quarter
  const int r16  = lane & 15;
  const int gq   = lane >> 4;
  const int ncol = wn * 16 + r16;
  const int b    = blockIdx.x >> 6;
  const int n0   = (blockIdx.x & 63) * 64;
  const float g  = gamma[0];

  const float* xb  = x  + (size_t)b * C_ * N_ + n0;
  const float* sab = sa + (size_t)b * C_ * N_ + n0;

  // A rows: h = (whf*4 + hf)*16 + r16 (rows 100..127 zero-padded in wab)
  const short* war = wab + (size_t)(whf * 64 + r16) * C_ + 8 * gq;

  // x staging assignment (2 float4 chunks per thread over 64x64 tile)
  const int xf0 = tid * 4, xf1 = (tid + 512) * 4;
  const int xk0 = xf0 >> 6, xn0 = xf0 & 63;
  const int xk1 = xf1 >> 6, xn1 = xf1 & 63;

  f32x4 acc[4];
#pragma unroll
  for (int f = 0; f < 4; ++f) acc[f] = (f32x4){0.f, 0.f, 0.f, 0.f};

  float4 xp0, xp1, sp0, sp1;

#define LOAD_TILE(c0)                                                        \
  do {                                                                       \
    xp0 = *(const float4*)&xb[(size_t)((c0) + xk0) * N_ + xn0];              \
    xp1 = *(const float4*)&xb[(size_t)((c0) + xk1) * N_ + xn1];              \
    if (g != 0.0f) {                                                         \
      sp0 = *(const float4*)&sab[(size_t)((c0) + xk0) * N_ + xn0];           \
      sp1 = *(const float4*)&sab[(size_t)((c0) + xk1) * N_ + xn1];           \
    }                                                                        \
  } while (0)

#define WRITE_TILE(buf)                                                      \
  do {                                                                       \
    float4 a0 = xp0, a1 = xp1;                                               \
    if (g != 0.0f) {                                                         \
      a0.x += g * sp0.x; a0.y += g * sp0.y; a0.z += g * sp0.z;               \
      a0.w += g * sp0.w;                                                     \
      a1.x += g * sp1.x; a1.y += g * sp1.y; a1.z += g * sp1.z;               \
      a1.w += g * sp1.w;                                                     \
    }                                                                        \
    bf16x4 p0 = {f2bf(a0.x), f2bf(a0.y), f2bf(a0.z), f2bf(a0.w)};            \
    bf16x4 p1 = {f2bf(a1.x), f2bf(a1.y), f2bf(a1.z), f2bf(a1.w)};            \
    *(bf16x4*)&xls[buf][xk0 * X_LDH + xn0] = p0;                             \
    *(bf16x4*)&xls[buf][xk1 * X_LDH + xn1] = p1;                             \
  } while (0)

#define COMPUTE(buf, c0)                                                     \
  do {                                                                       \
    _Pragma("unroll")                                                        \
    for (int ks = 0; ks < 2; ++ks) {                                         \
      const int k0 = ks * 32;                                                \
      bf16x8 bfrag;                                                          \
      _Pragma("unroll")                                                      \
      for (int e = 0; e < 8; ++e)                                            \
        bfrag[e] = xls[buf][(k0 + 8 * gq + e) * X_LDH + ncol];               \
      _Pragma("unroll")                                                      \
      for (int f = 0; f < 4; ++f) {                                          \
        bf16x8 afrag = *(const bf16x8*)                                      \
            &war[(size_t)(f * 16) * C_ + (c0) + k0];                         \
        acc[f] = __builtin_amdgcn_mfma_f32_16x16x32_bf16(afrag, bfrag,       \
                                                         acc[f], 0, 0, 0);   \
      }                                                                      \
    }                                                                        \
  } while (0)

  // prologue: tile 0
  LOAD_TILE(0);
  WRITE_TILE(0);
  __syncthreads();

#pragma unroll
  for (int t = 0; t < 8; ++t) {
    const int cur = t & 1;
    if (t + 1 < 8) LOAD_TILE((t + 1) * 64);   // issue next loads first
    COMPUTE(cur, t * 64);
    if (t + 1 < 8) WRITE_TILE(cur ^ 1);       // implicit vmcnt wait here
    __syncthreads();
  }

  // epilogue: score[n] = sum_h Wc[h] * tanh(acc + ba[h])
  float part = 0.f;
#pragma unroll
  for (int f = 0; f < 4; ++f) {
#pragma unroll
    for (int j = 0; j < 4; ++j) {
      int h = (whf * 4 + f) * 16 + gq * 4 + j;
      if (h < HID_) part += Wc[h] * fast_tanh(acc[f][j] + ba[h]);
    }
  }
  part += __shfl_xor(part, 16);
  part += __shfl_xor(part, 32);
  if (lane < 16) red[w][lane] = part;
  __syncthreads();
  if (tid < 64) {
    int q = tid >> 4, r = tid & 15;
    score[(size_t)b * N_ + n0 + q * 16 + r] = red[q][r] + red[q + 4][r];
  }
}

// softmax over n per batch
__global__ __launch_bounds__(256) void softmax_n(
    const float* __restrict__ score, float* __restrict__ amap) {
  const int b = blockIdx.x;
  const int tid = threadIdx.x;
  __shared__ float red4[4];
  float m = -1e30f;
  for (int i = tid; i < N_; i += 256) m = fmaxf(m, score[(size_t)b * N_ + i]);
#pragma unroll
  for (int off = 32; off; off >>= 1) m = fmaxf(m, __shfl_xor(m, off));
  if ((tid & 63) == 0) red4[tid >> 6] = m;
  __syncthreads();
  float M = fmaxf(fmaxf(red4[0], red4[1]), fmaxf(red4[2], red4[3]));
  __syncthreads();
  float s = 0.f;
  for (int i = tid; i < N_; i += 256) s += expf(score[(size_t)b * N_ + i] - M);
#pragma unroll
  for (int off = 32; off; off >>= 1) s += __shfl_xor(s, off);
  if ((tid & 63) == 0) red4[tid >> 6] = s;
  __syncthreads();
  float inv = 1.0f / (red4[0] + red4[1] + red4[2] + red4[3]);
  for (int i = tid; i < N_; i += 256)
    amap[(size_t)b * N_ + i] = expf(score[(size_t)b * N_ + i] - M) * inv;
}

// out[b,c] = sum_n x[b,c,n] * amap[b,n]
__global__ __launch_bounds__(256) void wsum_kernel(
    const float* __restrict__ x, const float* __restrict__ amap,
    float* __restrict__ out) {
  const int b = blockIdx.x >> 9;
  const int c = blockIdx.x & 511;
  const float4* xr = (const float4*)(x + ((size_t)b * C_ + c) * N_);
  const float4* am = (const float4*)(amap + (size_t)b * N_);
  float s = 0.f;
  for (int i = threadIdx.x; i < N_ / 4; i += 256) {
    float4 xv = xr[i];
    float4 av = am[i];
    s += xv.x * av.x + xv.y * av.y + xv.z * av.z + xv.w * av.w;
  }
#pragma unroll
  for (int off = 32; off; off >>= 1) s += __shfl_xor(s, off);
  __shared__ float red4[4];
  if ((threadIdx.x & 63) == 0) red4[threadIdx.x >> 6] = s;
  __syncthreads();
  if (threadIdx.x == 0)
    out[blockIdx.x] = red4[0] + red4[1] + red4[2] + red4[3];
}

extern "C" void kernel_launch(void* const* d_in, const int* in_sizes, int n_in,
                              void* d_out, int out_size, void* d_ws, size_t ws_size,
                              hipStream_t stream) {
  const float* x     = (const float*)d_in[0];
  const float* Wq    = (const float*)d_in[1];
  const float* bq    = (const float*)d_in[2];
  const float* Wk    = (const float*)d_in[3];
  const float* bk    = (const float*)d_in[4];
  const float* Wv    = (const float*)d_in[5];
  const float* bv    = (const float*)d_in[6];
  const float* gamma = (const float*)d_in[7];
  const float* Wa    = (const float*)d_in[8];
  const float* ba    = (const float*)d_in[9];
  const float* Wc    = (const float*)d_in[10];
  float* out = (float*)d_out;

  float* ws    = (float*)d_ws;
  float* score = ws;                          // B*N floats
  float* amap  = ws + 32768;                  // B*N floats
  short* wab   = (short*)(ws + 65536);        // 128*512 shorts (+slack)
  float* q  = ws + 65536 + 40960;
  float* k  = q + (size_t)B_ * D_ * N_;
  float* v  = k + (size_t)B_ * D_ * N_;
  float* sa = v + (size_t)B_ * C_ * N_;

  wa_to_bf16<<<64, 256, 0, stream>>>(Wa, wab);
  qkv_proj<<<256, 256, 0, stream>>>(x, Wq, bq, Wk, bk, Wv, bv, gamma, q, k, v);
  attn_sa<<<256, 256, 0, stream>>>(q, k, v, gamma, sa);
  pool_gemm<<<B_ * (N_ / 64), 512, 0, stream>>>(x, sa, gamma, wab, ba, Wc, score);
  softmax_n<<<B_, 256, 0, stream>>>(score, amap);
  wsum_kernel<<<B_ * C_, 256, 0, stream>>>(x, amap, out);
}